// Round 3
// baseline (391.224 us; speedup 1.0000x reference)
//
#include <hip/hip_runtime.h>
#include <math.h>

// ---------------------------------------------------------------------------
// Only sample 0 of the batch affects the loss (features[0], cap[0]).
//   kA grid 1088: blocks 0..1023 conv1+relu+pool -> p1[4][256][256]
//                 blocks 1024..1086: U[t] = hid_w[:, :300] @ cap0[t] + hid_b
//                 block 1087: zero vacc/asum/d_out, poison H with 0xAA
//   kB conv2+relu+pool fused with NetVLAD softmax+accumulate -> vacc, asum
//   kC vlad normalize (redundant per block) + FC slice -> feat[512]
//   kD sequential RNN, barrier-free: 8 blocks x 4 waves, each wave owns 16
//      rows full-width; W_h in VGPRs; DATA-AS-FLAG sync (H pre-poisoned
//      0xAA; sigmoid outputs can never be 0xAAAAAAAA); lane polls its 8
//      h-cells concurrently (1 MALL round trip), per-wave LDS stage, no
//      __syncthreads anywhere in the step loop.
//   kE y_t = sigmoid(out_w @ h_t + out_b); loss = mean((out-cap0)^2)
// ---------------------------------------------------------------------------

#define HPOISON 0xAAAAAAAAu

__device__ __forceinline__ float sigmoidf_(float x) {
  return 1.0f / (1.0f + __expf(-x));
}

// kA: conv1 / U / init fused. grid 1088 x 256.
__global__ __launch_bounds__(256) void k_front(const float* __restrict__ img,
                                               const float* __restrict__ w,
                                               const float* __restrict__ b,
                                               const float* __restrict__ hid_w,
                                               const float* __restrict__ hid_b,
                                               const float* __restrict__ cap,
                                               float* __restrict__ p1,
                                               float* __restrict__ U,
                                               float* __restrict__ vacc,
                                               float* __restrict__ asum,
                                               float* __restrict__ H,
                                               float* __restrict__ out) {
  int bx = blockIdx.x;
  int tid = threadIdx.x;
  if (bx < 1024) {
    // ---- conv1 + relu + pool ----
    int idx = bx * 256 + tid;
    int ox = idx & 255;
    int oy = (idx >> 8) & 255;
    int c  = idx >> 16;               // block-uniform
    __shared__ float wsh[27];
    __shared__ float bsh;
    if (tid < 27) wsh[tid] = w[c * 27 + tid];
    if (tid == 0) bsh = b[c];
    __syncthreads();
    int y0 = oy * 2 - 1, x0 = ox * 2 - 1;
    float a00, a01, a10, a11;
    a00 = a01 = a10 = a11 = bsh;
    #pragma unroll
    for (int ci = 0; ci < 3; ++ci) {
      float P[4][4];
      #pragma unroll
      for (int j = 0; j < 4; ++j) {
        int y = y0 + j;
        #pragma unroll
        for (int i = 0; i < 4; ++i) {
          int x = x0 + i;
          bool ok = ((unsigned)y < 512u) && ((unsigned)x < 512u);
          P[j][i] = ok ? img[ci * 262144 + y * 512 + x] : 0.0f;
        }
      }
      #pragma unroll
      for (int ky = 0; ky < 3; ++ky) {
        #pragma unroll
        for (int kx = 0; kx < 3; ++kx) {
          float wv = wsh[ci * 9 + ky * 3 + kx];
          a00 = fmaf(wv, P[ky][kx],         a00);
          a01 = fmaf(wv, P[ky][kx + 1],     a01);
          a10 = fmaf(wv, P[ky + 1][kx],     a10);
          a11 = fmaf(wv, P[ky + 1][kx + 1], a11);
        }
      }
    }
    p1[idx] = 0.25f * (fmaxf(a00, 0.f) + fmaxf(a01, 0.f) +
                       fmaxf(a10, 0.f) + fmaxf(a11, 0.f));
    return;
  }
  if (bx < 1087) {
    // ---- U[t] = hid_w[:, :300] @ cap0[t] + hid_b ----
    int t = bx - 1024;
    __shared__ __align__(16) float csh[300];
    if (tid < 256) csh[tid] = cap[t * 300 + tid];
    if (tid < 44) csh[256 + tid] = cap[t * 300 + 256 + tid];
    __syncthreads();
    #pragma unroll
    for (int rr = 0; rr < 2; ++rr) {
      int r = tid + rr * 256;
      float acc = hid_b[r];
      const float4* w4 = (const float4*)(hid_w + r * 812);
      const float4* c4 = (const float4*)csh;
      #pragma unroll 5
      for (int i = 0; i < 75; ++i) {
        float4 aa = w4[i]; float4 xx = c4[i];
        acc = fmaf(aa.x, xx.x, acc); acc = fmaf(aa.y, xx.y, acc);
        acc = fmaf(aa.z, xx.z, acc); acc = fmaf(aa.w, xx.w, acc);
      }
      U[t * 512 + r] = acc;
    }
    return;
  }
  // ---- init block ----
  for (int i = tid; i < 1024; i += 256) vacc[i] = 0.f;
  if (tid < 64) asum[tid] = 0.f;
  if (tid == 0) out[0] = 0.f;
  uint4* Hu4 = (uint4*)H;
  uint4 pz = make_uint4(HPOISON, HPOISON, HPOISON, HPOISON);
  for (int i = tid; i < (63 * 512) / 4; i += 256) Hu4[i] = pz;
}

// kB: conv2+relu+pool fused with NetVLAD. grid 64x256.
#define PS_STRIDE 65
#define XS_STRIDE 20
__global__ __launch_bounds__(256, 1) void k_conv2vlad(const float* __restrict__ p1,
                                                      const float* __restrict__ w2,
                                                      const float* __restrict__ b2,
                                                      const float* __restrict__ nvw,
                                                      const float* __restrict__ nvb,
                                                      float* __restrict__ vacc,
                                                      float* __restrict__ asum) {
  __shared__ __align__(16) float ps[128 * PS_STRIDE];  // 33.3 KB
  __shared__ __align__(16) float xs[128 * XS_STRIDE];  // 10.2 KB
  __shared__ float wsh[1024];
  __shared__ float bsh[64];
  __shared__ float aS[256];
  __shared__ float cw[576];
  __shared__ float cb[16];
  int tid = threadIdx.x;
  for (int i = tid; i < 1024; i += 256) wsh[i] = nvw[i];
  if (tid < 64) bsh[tid] = nvb[tid];
  for (int i = tid; i < 576; i += 256) cw[i] = w2[i];
  if (tid < 16) cb[tid] = b2[tid];
  __syncthreads();

  int ox = tid & 127;
  int oyl = tid >> 7;
  int oy = blockIdx.x * 2 + oyl;
  int y0 = oy * 2 - 1, x0 = ox * 2 - 1;
  float a[16][4];
  #pragma unroll
  for (int oc = 0; oc < 16; ++oc) {
    float bb = cb[oc];
    a[oc][0] = bb; a[oc][1] = bb; a[oc][2] = bb; a[oc][3] = bb;
  }
  #pragma unroll
  for (int ci = 0; ci < 4; ++ci) {
    float P[4][4];
    #pragma unroll
    for (int j = 0; j < 4; ++j) {
      int y = y0 + j;
      #pragma unroll
      for (int i = 0; i < 4; ++i) {
        int x = x0 + i;
        bool ok = ((unsigned)y < 256u) && ((unsigned)x < 256u);
        P[j][i] = ok ? p1[ci * 65536 + y * 256 + x] : 0.0f;
      }
    }
    #pragma unroll
    for (int oc = 0; oc < 16; ++oc) {
      #pragma unroll
      for (int ky = 0; ky < 3; ++ky) {
        #pragma unroll
        for (int kx = 0; kx < 3; ++kx) {
          float wv = cw[oc * 36 + ci * 9 + ky * 3 + kx];
          a[oc][0] = fmaf(wv, P[ky][kx],         a[oc][0]);
          a[oc][1] = fmaf(wv, P[ky][kx + 1],     a[oc][1]);
          a[oc][2] = fmaf(wv, P[ky + 1][kx],     a[oc][2]);
          a[oc][3] = fmaf(wv, P[ky + 1][kx + 1], a[oc][3]);
        }
      }
    }
  }
  float x[16];
  #pragma unroll
  for (int oc = 0; oc < 16; ++oc)
    x[oc] = 0.25f * (fmaxf(a[oc][0], 0.f) + fmaxf(a[oc][1], 0.f) +
                     fmaxf(a[oc][2], 0.f) + fmaxf(a[oc][3], 0.f));

  float p[64];
  float m = -1e30f;
  #pragma unroll
  for (int k = 0; k < 64; ++k) {
    float acc = bsh[k];
    #pragma unroll
    for (int c = 0; c < 16; ++c) acc = fmaf(wsh[k * 16 + c], x[c], acc);
    p[k] = acc;
    m = fmaxf(m, acc);
  }
  float s = 0.f;
  #pragma unroll
  for (int k = 0; k < 64; ++k) { p[k] = __expf(p[k] - m); s += p[k]; }
  float inv = 1.0f / s;
  #pragma unroll
  for (int k = 0; k < 64; ++k) p[k] *= inv;

  int q = tid >> 6, k = tid & 63;
  float acc[16];
  #pragma unroll
  for (int c = 0; c < 16; ++c) acc[c] = 0.f;
  float accA = 0.f;

  for (int pass = 0; pass < 2; ++pass) {
    __syncthreads();
    if ((tid >> 7) == pass) {
      int tt = tid & 127;
      #pragma unroll
      for (int kk = 0; kk < 64; ++kk) ps[tt * PS_STRIDE + kk] = p[kk];
      #pragma unroll
      for (int c = 0; c < 16; ++c) xs[tt * XS_STRIDE + c] = x[c];
    }
    __syncthreads();
    #pragma unroll
    for (int j = 0; j < 32; ++j) {
      int tt = q * 32 + j;
      float pv = ps[tt * PS_STRIDE + k];
      accA += pv;
      const float4* xv = (const float4*)(xs + tt * XS_STRIDE);
      #pragma unroll
      for (int c4 = 0; c4 < 4; ++c4) {
        float4 xx = xv[c4];
        acc[c4 * 4 + 0] = fmaf(pv, xx.x, acc[c4 * 4 + 0]);
        acc[c4 * 4 + 1] = fmaf(pv, xx.y, acc[c4 * 4 + 1]);
        acc[c4 * 4 + 2] = fmaf(pv, xx.z, acc[c4 * 4 + 2]);
        acc[c4 * 4 + 3] = fmaf(pv, xx.w, acc[c4 * 4 + 3]);
      }
    }
  }
  __syncthreads();
  float* red = ps;
  #pragma unroll
  for (int c = 0; c < 16; ++c) red[tid * 16 + c] = acc[c];
  aS[tid] = accA;
  __syncthreads();
  if (q == 0) {
    float aa = aS[k] + aS[64 + k] + aS[128 + k] + aS[192 + k];
    atomicAdd(&asum[k], aa);
  }
  int k2 = tid >> 2;
  int cg = (tid & 3) * 4;
  #pragma unroll
  for (int cc = 0; cc < 4; ++cc) {
    int c = cg + cc;
    float v = red[(0 * 64 + k2) * 16 + c] + red[(1 * 64 + k2) * 16 + c] +
              red[(2 * 64 + k2) * 16 + c] + red[(3 * 64 + k2) * 16 + c];
    atomicAdd(&vacc[k2 * 16 + c], v);
  }
}

// kC: vlad-normalize (redundant per block) + FC slice. grid 8 x 512.
__global__ __launch_bounds__(512) void k_fc(const float* __restrict__ vacc,
                                            const float* __restrict__ asum,
                                            const float* __restrict__ cent,
                                            const float* __restrict__ fcw,
                                            const float* __restrict__ fcb,
                                            float* __restrict__ feat) {
  int tid = threadIdx.x;
  int q = blockIdx.x;
  __shared__ __align__(16) float v[1024];
  __shared__ float rn[64];
  __shared__ float red[9];
  for (int i = tid; i < 1024; i += 512)
    v[i] = vacc[i] - asum[i >> 4] * cent[i];
  __syncthreads();
  if (tid < 64) {
    float ss = 0.f;
    #pragma unroll
    for (int c = 0; c < 16; ++c) { float xx = v[tid * 16 + c]; ss = fmaf(xx, xx, ss); }
    rn[tid] = fmaxf(sqrtf(ss), 1e-12f);
  }
  __syncthreads();
  float gs = 0.f;
  for (int i = tid; i < 1024; i += 512) {
    float nv = v[i] / rn[i >> 4];
    v[i] = nv;
    gs = fmaf(nv, nv, gs);
  }
  #pragma unroll
  for (int o = 32; o > 0; o >>= 1) gs += __shfl_down(gs, o);
  int wv = tid >> 6, lane = tid & 63;
  if (lane == 0) red[wv] = gs;
  __syncthreads();
  if (tid == 0) {
    float tot = 0.f;
    #pragma unroll
    for (int qq = 0; qq < 8; ++qq) tot += red[qq];
    red[8] = 1.0f / fmaxf(sqrtf(tot), 1e-12f);
  }
  __syncthreads();
  float invg = red[8];
  int r = q * 64 + (tid >> 3);
  int cch = tid & 7;
  float acc = 0.f;
  const float4* fw4 = (const float4*)(fcw + r * 1024 + cch * 128);
  const float4* v4  = (const float4*)(v + cch * 128);
  #pragma unroll 4
  for (int i = 0; i < 32; ++i) {
    float4 aa = fw4[i]; float4 xx = v4[i];
    acc = fmaf(aa.x, xx.x, acc); acc = fmaf(aa.y, xx.y, acc);
    acc = fmaf(aa.z, xx.z, acc); acc = fmaf(aa.w, xx.w, acc);
  }
  acc += __shfl_down(acc, 4, 8);
  acc += __shfl_down(acc, 2, 8);
  acc += __shfl_down(acc, 1, 8);
  if (cch == 0) feat[r] = fmaf(invg, acc, fcb[r]);
}

// kD: barrier-free sequential RNN. 8 blocks x 256.
// Wave wv of block b owns rows [b*64+wv*16, +16), full 512-col width.
// Lane L = r*4+cg: row = base+r, col chunk [cg*128, +128); polls h cells
// [L*8, L*8+8) concurrently; per-wave LDS stage; 2 shfl_xor reduce.
__global__ __launch_bounds__(256, 1) void k_rnn(const float* __restrict__ hid_w,
                                                const float* __restrict__ U,
                                                const float* __restrict__ feat,
                                                float* __restrict__ H) {
  const int tid = threadIdx.x;
  const int wv = tid >> 6;
  const int lane = tid & 63;
  const int r = lane >> 2;
  const int cg = lane & 3;
  const int row = blockIdx.x * 64 + wv * 16 + r;
  const int colbase = cg * 128;
  float4 wr[32];
  const float4* wp = (const float4*)(hid_w + row * 812 + 300 + colbase);
  #pragma unroll
  for (int i = 0; i < 32; ++i) wr[i] = wp[i];
  __shared__ __align__(16) float hsh[4][512];
  float* hw = hsh[wv];
  unsigned int* Hu = (unsigned int*)H;
  const int pbase = lane * 8;
  for (int t = 0; t < 63; ++t) {
    float uval = U[t * 512 + row];       // in flight during the poll
    if (t == 0) {
      float4 f0 = *(const float4*)(feat + pbase);
      float4 f1 = *(const float4*)(feat + pbase + 4);
      *(float4*)(hw + pbase) = f0;
      *(float4*)(hw + pbase + 4) = f1;
    } else {
      const unsigned int* src = Hu + (t - 1) * 512 + pbase;
      unsigned int a[8];
      bool again;
      do {
        #pragma unroll
        for (int j = 0; j < 8; ++j)
          a[j] = __hip_atomic_load(src + j, __ATOMIC_RELAXED,
                                   __HIP_MEMORY_SCOPE_AGENT);
        again = false;
        #pragma unroll
        for (int j = 0; j < 8; ++j) again = again || (a[j] == HPOISON);
      } while (again);
      #pragma unroll
      for (int j = 0; j < 8; ++j) hw[pbase + j] = __uint_as_float(a[j]);
    }
    __builtin_amdgcn_wave_barrier();     // keep LDS writes before reads
    float acc = 0.0f;
    #pragma unroll
    for (int i = 0; i < 32; ++i) {
      float4 hv = *(const float4*)(hw + colbase + i * 4);
      acc = fmaf(wr[i].x, hv.x, acc);
      acc = fmaf(wr[i].y, hv.y, acc);
      acc = fmaf(wr[i].z, hv.z, acc);
      acc = fmaf(wr[i].w, hv.w, acc);
    }
    acc += __shfl_xor(acc, 1);
    acc += __shfl_xor(acc, 2);
    float hn = sigmoidf_(acc + uval);
    if (cg == 0)
      __hip_atomic_store(Hu + t * 512 + row, __float_as_uint(hn),
                         __ATOMIC_RELAXED, __HIP_MEMORY_SCOPE_AGENT);
    __builtin_amdgcn_wave_barrier();     // keep next-iter writes after reads
  }
}

// kE: y_t = sigmoid(out_w @ h_t + out_b); accumulate squared error. grid 63x512.
__global__ __launch_bounds__(512) void k_loss(const float* __restrict__ outw,
                                              const float* __restrict__ outb,
                                              const float* __restrict__ H,
                                              const float* __restrict__ cap,
                                              float* __restrict__ loss) {
  int t = blockIdx.x;
  int tid = threadIdx.x;
  __shared__ __align__(16) float hsh[512];
  __shared__ float red[8];
  hsh[tid] = H[t * 512 + tid];
  __syncthreads();
  float se = 0.f;
  if (tid < 300) {
    float acc = outb[tid];
    const float4* w4 = (const float4*)(outw + tid * 512);
    const float4* h4 = (const float4*)hsh;
    #pragma unroll 4
    for (int i = 0; i < 128; ++i) {
      float4 aa = w4[i]; float4 xx = h4[i];
      acc = fmaf(aa.x, xx.x, acc); acc = fmaf(aa.y, xx.y, acc);
      acc = fmaf(aa.z, xx.z, acc); acc = fmaf(aa.w, xx.w, acc);
    }
    float y = sigmoidf_(acc);
    float d = y - cap[(t + 1) * 300 + tid];
    se = d * d;
  }
  #pragma unroll
  for (int o = 32; o > 0; o >>= 1) se += __shfl_down(se, o);
  if ((tid & 63) == 0) red[tid >> 6] = se;
  __syncthreads();
  if (tid == 0) {
    float tot = 0.f;
    #pragma unroll
    for (int qq = 0; qq < 8; ++qq) tot += red[qq];
    atomicAdd(loss, tot * (1.0f / 19200.0f));
  }
}

extern "C" void kernel_launch(void* const* d_in, const int* in_sizes, int n_in,
                              void* d_out, int out_size, void* d_ws, size_t ws_size,
                              hipStream_t stream) {
  (void)in_sizes; (void)n_in; (void)out_size; (void)ws_size;
  const float* img  = (const float*)d_in[0];   // sample 0 only
  const float* cap  = (const float*)d_in[1];   // sample 0 only
  const float* c1w  = (const float*)d_in[2];
  const float* c1b  = (const float*)d_in[3];
  const float* c2w  = (const float*)d_in[4];
  const float* c2b  = (const float*)d_in[5];
  const float* cent = (const float*)d_in[6];
  const float* nvw  = (const float*)d_in[7];
  const float* nvb  = (const float*)d_in[8];
  const float* fcw  = (const float*)d_in[9];
  const float* fcb  = (const float*)d_in[10];
  const float* hidw = (const float*)d_in[11];
  const float* hidb = (const float*)d_in[12];
  const float* outw = (const float*)d_in[13];
  const float* outb = (const float*)d_in[14];

  float* ws   = (float*)d_ws;
  float* p1   = ws;               // 262144
  float* vacc = ws + 262144;      // 1024
  float* asum = ws + 263168;      // 64
  float* feat = ws + 263232;      // 512
  float* U    = ws + 263744;      // 63*512 = 32256
  float* H    = ws + 296000;      // 63*512 = 32256

  k_front<<<1088, 256, 0, stream>>>(img, c1w, c1b, hidw, hidb, cap,
                                    p1, U, vacc, asum, H, (float*)d_out);
  k_conv2vlad<<<64, 256, 0, stream>>>(p1, c2w, c2b, nvw, nvb, vacc, asum);
  k_fc<<<8, 512, 0, stream>>>(vacc, asum, cent, fcw, fcb, feat);
  k_rnn<<<8, 256, 0, stream>>>(hidw, U, feat, H);
  k_loss<<<63, 512, 0, stream>>>(outw, outb, H, cap, (float*)d_out);
}

// Round 4
// 267.590 us; speedup vs baseline: 1.4620x; 1.4620x over previous
//
#include <hip/hip_runtime.h>
#include <math.h>

// ---------------------------------------------------------------------------
// Only sample 0 of the batch affects the loss (features[0], cap[0]).
// 3 kernels:
//  KA k_front  grid 1088x256: conv1+relu+pool -> p1 ; U[t]=hid_w[:,:300]@cap0[t]
//              + hid_b ; init block zeros vacc/asum/done/loss, poisons H(0xAA).
//  KB k_mid    grid 64x256: conv2+relu+pool fused with NetVLAD softmax+
//              accumulate (atomics) ; intra-grid completion counter (all 64
//              blocks co-resident, spinners can't starve others -> no
//              deadlock) ; then each block computes 8 rows of the FC ->
//              feat[512].
//  KC k_back   grid 67x512: blocks 0..3 = sequential RNN (128 rows each, W_h
//              in VGPRs, DATA-AS-FLAG sync: H pre-poisoned 0xAA, sigmoid
//              outputs have sign bit 0 so can never equal 0xAAAAAAAA; one
//              cell polled per thread; swizzled LDS stage, conflict-free).
//              Blocks 4..66 = loss rows, poll their H row with s_sleep
//              backoff, fully overlapped with the recurrence.
// ---------------------------------------------------------------------------

#define HPOISON 0xAAAAAAAAu

__device__ __forceinline__ float sigmoidf_(float x) {
  return 1.0f / (1.0f + __expf(-x));
}

// KA: conv1 / U / init fused. grid 1088 x 256.
__global__ __launch_bounds__(256) void k_front(const float* __restrict__ img,
                                               const float* __restrict__ w,
                                               const float* __restrict__ b,
                                               const float* __restrict__ hid_w,
                                               const float* __restrict__ hid_b,
                                               const float* __restrict__ cap,
                                               float* __restrict__ p1,
                                               float* __restrict__ U,
                                               float* __restrict__ vacc,
                                               float* __restrict__ asum,
                                               float* __restrict__ H,
                                               int* __restrict__ done,
                                               float* __restrict__ out) {
  int bx = blockIdx.x;
  int tid = threadIdx.x;
  if (bx < 1024) {
    // ---- conv1 + relu + pool ----
    int idx = bx * 256 + tid;
    int ox = idx & 255;
    int oy = (idx >> 8) & 255;
    int c  = idx >> 16;               // block-uniform
    __shared__ float wsh[27];
    __shared__ float bsh;
    if (tid < 27) wsh[tid] = w[c * 27 + tid];
    if (tid == 0) bsh = b[c];
    __syncthreads();
    int y0 = oy * 2 - 1, x0 = ox * 2 - 1;
    float a00, a01, a10, a11;
    a00 = a01 = a10 = a11 = bsh;
    #pragma unroll
    for (int ci = 0; ci < 3; ++ci) {
      float P[4][4];
      #pragma unroll
      for (int j = 0; j < 4; ++j) {
        int y = y0 + j;
        #pragma unroll
        for (int i = 0; i < 4; ++i) {
          int x = x0 + i;
          bool ok = ((unsigned)y < 512u) && ((unsigned)x < 512u);
          P[j][i] = ok ? img[ci * 262144 + y * 512 + x] : 0.0f;
        }
      }
      #pragma unroll
      for (int ky = 0; ky < 3; ++ky) {
        #pragma unroll
        for (int kx = 0; kx < 3; ++kx) {
          float wv = wsh[ci * 9 + ky * 3 + kx];
          a00 = fmaf(wv, P[ky][kx],         a00);
          a01 = fmaf(wv, P[ky][kx + 1],     a01);
          a10 = fmaf(wv, P[ky + 1][kx],     a10);
          a11 = fmaf(wv, P[ky + 1][kx + 1], a11);
        }
      }
    }
    p1[idx] = 0.25f * (fmaxf(a00, 0.f) + fmaxf(a01, 0.f) +
                       fmaxf(a10, 0.f) + fmaxf(a11, 0.f));
    return;
  }
  if (bx < 1087) {
    // ---- U[t] = hid_w[:, :300] @ cap0[t] + hid_b ----
    int t = bx - 1024;
    __shared__ __align__(16) float csh[300];
    if (tid < 256) csh[tid] = cap[t * 300 + tid];
    if (tid < 44) csh[256 + tid] = cap[t * 300 + 256 + tid];
    __syncthreads();
    #pragma unroll
    for (int rr = 0; rr < 2; ++rr) {
      int r = tid + rr * 256;
      float acc = hid_b[r];
      const float4* w4 = (const float4*)(hid_w + r * 812);
      const float4* c4 = (const float4*)csh;
      #pragma unroll 5
      for (int i = 0; i < 75; ++i) {
        float4 aa = w4[i]; float4 xx = c4[i];
        acc = fmaf(aa.x, xx.x, acc); acc = fmaf(aa.y, xx.y, acc);
        acc = fmaf(aa.z, xx.z, acc); acc = fmaf(aa.w, xx.w, acc);
      }
      U[t * 512 + r] = acc;
    }
    return;
  }
  // ---- init block ----
  for (int i = tid; i < 1024; i += 256) vacc[i] = 0.f;
  if (tid < 64) asum[tid] = 0.f;
  if (tid == 0) { out[0] = 0.f; done[0] = 0; }
  uint4* Hu4 = (uint4*)H;
  uint4 pz = make_uint4(HPOISON, HPOISON, HPOISON, HPOISON);
  for (int i = tid; i < (63 * 512) / 4; i += 256) Hu4[i] = pz;
}

// KB: conv2+relu+pool fused with NetVLAD, then FC after grid-wide counter.
#define PS_STRIDE 65
#define XS_STRIDE 20
__global__ __launch_bounds__(256, 1) void k_mid(const float* __restrict__ p1,
                                                const float* __restrict__ w2,
                                                const float* __restrict__ b2,
                                                const float* __restrict__ nvw,
                                                const float* __restrict__ nvb,
                                                const float* __restrict__ cent,
                                                const float* __restrict__ fcw,
                                                const float* __restrict__ fcb,
                                                float* __restrict__ vacc,
                                                float* __restrict__ asum,
                                                float* __restrict__ feat,
                                                int* __restrict__ done) {
  __shared__ __align__(16) float ps[128 * PS_STRIDE];  // 33.3 KB
  __shared__ __align__(16) float xs[128 * XS_STRIDE];  // 10.2 KB
  __shared__ float wsh[1024];
  __shared__ float bsh[64];
  __shared__ float aS[256];
  __shared__ float cw[576];
  __shared__ float cb[16];
  __shared__ float fcred[12];
  int tid = threadIdx.x;
  for (int i = tid; i < 1024; i += 256) wsh[i] = nvw[i];
  if (tid < 64) bsh[tid] = nvb[tid];
  for (int i = tid; i < 576; i += 256) cw[i] = w2[i];
  if (tid < 16) cb[tid] = b2[tid];
  __syncthreads();

  int ox = tid & 127;
  int oyl = tid >> 7;
  int oy = blockIdx.x * 2 + oyl;
  int y0 = oy * 2 - 1, x0 = ox * 2 - 1;
  float a[16][4];
  #pragma unroll
  for (int oc = 0; oc < 16; ++oc) {
    float bb = cb[oc];
    a[oc][0] = bb; a[oc][1] = bb; a[oc][2] = bb; a[oc][3] = bb;
  }
  #pragma unroll
  for (int ci = 0; ci < 4; ++ci) {
    float P[4][4];
    #pragma unroll
    for (int j = 0; j < 4; ++j) {
      int y = y0 + j;
      #pragma unroll
      for (int i = 0; i < 4; ++i) {
        int x = x0 + i;
        bool ok = ((unsigned)y < 256u) && ((unsigned)x < 256u);
        P[j][i] = ok ? p1[ci * 65536 + y * 256 + x] : 0.0f;
      }
    }
    #pragma unroll
    for (int oc = 0; oc < 16; ++oc) {
      #pragma unroll
      for (int ky = 0; ky < 3; ++ky) {
        #pragma unroll
        for (int kx = 0; kx < 3; ++kx) {
          float wv = cw[oc * 36 + ci * 9 + ky * 3 + kx];
          a[oc][0] = fmaf(wv, P[ky][kx],         a[oc][0]);
          a[oc][1] = fmaf(wv, P[ky][kx + 1],     a[oc][1]);
          a[oc][2] = fmaf(wv, P[ky + 1][kx],     a[oc][2]);
          a[oc][3] = fmaf(wv, P[ky + 1][kx + 1], a[oc][3]);
        }
      }
    }
  }
  float x[16];
  #pragma unroll
  for (int oc = 0; oc < 16; ++oc)
    x[oc] = 0.25f * (fmaxf(a[oc][0], 0.f) + fmaxf(a[oc][1], 0.f) +
                     fmaxf(a[oc][2], 0.f) + fmaxf(a[oc][3], 0.f));

  float p[64];
  float m = -1e30f;
  #pragma unroll
  for (int k = 0; k < 64; ++k) {
    float acc = bsh[k];
    #pragma unroll
    for (int c = 0; c < 16; ++c) acc = fmaf(wsh[k * 16 + c], x[c], acc);
    p[k] = acc;
    m = fmaxf(m, acc);
  }
  float s = 0.f;
  #pragma unroll
  for (int k = 0; k < 64; ++k) { p[k] = __expf(p[k] - m); s += p[k]; }
  float inv = 1.0f / s;
  #pragma unroll
  for (int k = 0; k < 64; ++k) p[k] *= inv;

  int q = tid >> 6, k = tid & 63;
  float acc[16];
  #pragma unroll
  for (int c = 0; c < 16; ++c) acc[c] = 0.f;
  float accA = 0.f;

  for (int pass = 0; pass < 2; ++pass) {
    __syncthreads();
    if ((tid >> 7) == pass) {
      int tt = tid & 127;
      #pragma unroll
      for (int kk = 0; kk < 64; ++kk) ps[tt * PS_STRIDE + kk] = p[kk];
      #pragma unroll
      for (int c = 0; c < 16; ++c) xs[tt * XS_STRIDE + c] = x[c];
    }
    __syncthreads();
    #pragma unroll
    for (int j = 0; j < 32; ++j) {
      int tt = q * 32 + j;
      float pv = ps[tt * PS_STRIDE + k];
      accA += pv;
      const float4* xv = (const float4*)(xs + tt * XS_STRIDE);
      #pragma unroll
      for (int c4 = 0; c4 < 4; ++c4) {
        float4 xx = xv[c4];
        acc[c4 * 4 + 0] = fmaf(pv, xx.x, acc[c4 * 4 + 0]);
        acc[c4 * 4 + 1] = fmaf(pv, xx.y, acc[c4 * 4 + 1]);
        acc[c4 * 4 + 2] = fmaf(pv, xx.z, acc[c4 * 4 + 2]);
        acc[c4 * 4 + 3] = fmaf(pv, xx.w, acc[c4 * 4 + 3]);
      }
    }
  }
  __syncthreads();
  float* red = ps;
  #pragma unroll
  for (int c = 0; c < 16; ++c) red[tid * 16 + c] = acc[c];
  aS[tid] = accA;
  __syncthreads();
  if (q == 0) {
    float aa = aS[k] + aS[64 + k] + aS[128 + k] + aS[192 + k];
    atomicAdd(&asum[k], aa);
  }
  int k2 = tid >> 2;
  int cg = (tid & 3) * 4;
  #pragma unroll
  for (int cc = 0; cc < 4; ++cc) {
    int c = cg + cc;
    float v = red[(0 * 64 + k2) * 16 + c] + red[(1 * 64 + k2) * 16 + c] +
              red[(2 * 64 + k2) * 16 + c] + red[(3 * 64 + k2) * 16 + c];
    atomicAdd(&vacc[k2 * 16 + c], v);
  }
  // ---- grid-wide completion: __syncthreads drains vmcnt (atomics acked at
  // MALL) for every wave, then one counter tick; all 64 blocks co-resident.
  __syncthreads();
  if (tid == 0) {
    __hip_atomic_fetch_add(done, 1, __ATOMIC_RELAXED, __HIP_MEMORY_SCOPE_AGENT);
    while (__hip_atomic_load(done, __ATOMIC_RELAXED,
                             __HIP_MEMORY_SCOPE_AGENT) < 64)
      __builtin_amdgcn_s_sleep(2);
  }
  __syncthreads();
  // ---- FC: block computes rows [bx*8, bx*8+8) of feat ----
  float* v = ps;   // reuse as [1024]
  for (int i = tid; i < 1024; i += 256) {
    float vc = __hip_atomic_load(vacc + i, __ATOMIC_RELAXED,
                                 __HIP_MEMORY_SCOPE_AGENT);
    float as = __hip_atomic_load(asum + (i >> 4), __ATOMIC_RELAXED,
                                 __HIP_MEMORY_SCOPE_AGENT);
    v[i] = vc - as * cent[i];
  }
  __syncthreads();
  if (tid < 64) {
    float ss = 0.f;
    #pragma unroll
    for (int c = 0; c < 16; ++c) { float xx = v[tid * 16 + c]; ss = fmaf(xx, xx, ss); }
    aS[tid] = fmaxf(sqrtf(ss), 1e-12f);
  }
  __syncthreads();
  float gs = 0.f;
  for (int i = tid; i < 1024; i += 256) {
    float nv = v[i] / aS[i >> 4];
    v[i] = nv;
    gs = fmaf(nv, nv, gs);
  }
  #pragma unroll
  for (int o = 32; o > 0; o >>= 1) gs += __shfl_down(gs, o);
  if ((tid & 63) == 0) fcred[tid >> 6] = gs;
  __syncthreads();
  if (tid == 0) {
    float tot = fcred[0] + fcred[1] + fcred[2] + fcred[3];
    fcred[8] = 1.0f / fmaxf(sqrtf(tot), 1e-12f);
  }
  __syncthreads();
  float invg = fcred[8];
  int rl = tid >> 5;            // 0..7
  int ch = tid & 31;            // 32-col chunk of 1024
  int row = blockIdx.x * 8 + rl;
  float fa = 0.f;
  const float4* fw4 = (const float4*)(fcw + row * 1024 + ch * 32);
  const float4* v4  = (const float4*)(v + ch * 32);
  #pragma unroll
  for (int i = 0; i < 8; ++i) {
    float4 aa = fw4[i]; float4 xx = v4[i];
    fa = fmaf(aa.x, xx.x, fa); fa = fmaf(aa.y, xx.y, fa);
    fa = fmaf(aa.z, xx.z, fa); fa = fmaf(aa.w, xx.w, fa);
  }
  fa += __shfl_xor(fa, 16);
  fa += __shfl_xor(fa, 8);
  fa += __shfl_xor(fa, 4);
  fa += __shfl_xor(fa, 2);
  fa += __shfl_xor(fa, 1);
  if (ch == 0) feat[row] = fmaf(invg, fa, fcb[row]);
}

// KC: RNN (blocks 0..3) + loss (blocks 4..66). 67 blocks x 512 threads.
// RNN: block owns 128 rows; thread = (row = bx*128 + tid>>2, cols
// [(tid&3)*128, +128)); one H cell polled per thread; swizzled LDS stage
// (chunk k at offset k*136 -> banks 8k..8k+3, conflict-free reads/writes).
__global__ __launch_bounds__(512, 1) void k_back(const float* __restrict__ hid_w,
                                                 const float* __restrict__ U,
                                                 const float* __restrict__ feat,
                                                 float* __restrict__ H,
                                                 const float* __restrict__ outw,
                                                 const float* __restrict__ outb,
                                                 const float* __restrict__ cap,
                                                 float* __restrict__ loss) {
  int tid = threadIdx.x;
  unsigned int* Hu = (unsigned int*)H;
  if (blockIdx.x < 4) {
    const int cg = tid & 3;
    const int r  = tid >> 2;                 // 0..127
    const int row = blockIdx.x * 128 + r;
    const int rb = cg * 136;                 // swizzled read base
    const int swi = ((tid >> 7) * 136) + (tid & 127);  // swizzled write idx
    float4 wr[32];
    const float4* wp = (const float4*)(hid_w + row * 812 + 300 + cg * 128);
    #pragma unroll
    for (int i = 0; i < 32; ++i) wr[i] = wp[i];
    __shared__ __align__(16) float hsh[544];
    for (int t = 0; t < 63; ++t) {
      float uval = U[t * 512 + row];         // overlapped with the poll
      float hv;
      if (t == 0) {
        hv = feat[tid];
      } else {
        const unsigned int* src = Hu + (t - 1) * 512 + tid;
        unsigned int a;
        do {
          a = __hip_atomic_load(src, __ATOMIC_RELAXED,
                                __HIP_MEMORY_SCOPE_AGENT);
        } while (a == HPOISON);
        hv = __uint_as_float(a);
      }
      hsh[swi] = hv;
      __syncthreads();
      float acc = 0.f;
      #pragma unroll
      for (int i = 0; i < 32; ++i) {
        float4 h4 = *(const float4*)(hsh + rb + i * 4);
        acc = fmaf(wr[i].x, h4.x, acc);
        acc = fmaf(wr[i].y, h4.y, acc);
        acc = fmaf(wr[i].z, h4.z, acc);
        acc = fmaf(wr[i].w, h4.w, acc);
      }
      acc += __shfl_xor(acc, 1);
      acc += __shfl_xor(acc, 2);
      if (cg == 0) {
        float hn = sigmoidf_(acc + uval);
        __hip_atomic_store(Hu + t * 512 + row, __float_as_uint(hn),
                           __ATOMIC_RELAXED, __HIP_MEMORY_SCOPE_AGENT);
      }
      __syncthreads();                       // hsh reuse next iter
    }
    return;
  }
  // ---- loss block for timestep t: poll own H row (data-as-flag), compute ----
  int t = blockIdx.x - 4;
  __shared__ __align__(16) float hsh2[512];
  __shared__ float red2[8];
  {
    const unsigned int* src = Hu + t * 512 + tid;
    unsigned int a;
    for (;;) {
      a = __hip_atomic_load(src, __ATOMIC_RELAXED, __HIP_MEMORY_SCOPE_AGENT);
      if (a != HPOISON) break;
      __builtin_amdgcn_s_sleep(16);          // low-traffic backoff
    }
    hsh2[tid] = __uint_as_float(a);
  }
  __syncthreads();
  float se = 0.f;
  if (tid < 300) {
    float acc = outb[tid];
    const float4* w4 = (const float4*)(outw + tid * 512);
    const float4* h4 = (const float4*)hsh2;
    #pragma unroll 4
    for (int i = 0; i < 128; ++i) {
      float4 aa = w4[i]; float4 xx = h4[i];
      acc = fmaf(aa.x, xx.x, acc); acc = fmaf(aa.y, xx.y, acc);
      acc = fmaf(aa.z, xx.z, acc); acc = fmaf(aa.w, xx.w, acc);
    }
    float y = sigmoidf_(acc);
    float d = y - cap[(t + 1) * 300 + tid];
    se = d * d;
  }
  #pragma unroll
  for (int o = 32; o > 0; o >>= 1) se += __shfl_down(se, o);
  if ((tid & 63) == 0) red2[tid >> 6] = se;
  __syncthreads();
  if (tid == 0) {
    float tot = 0.f;
    #pragma unroll
    for (int qq = 0; qq < 8; ++qq) tot += red2[qq];
    atomicAdd(loss, tot * (1.0f / 19200.0f));
  }
}

extern "C" void kernel_launch(void* const* d_in, const int* in_sizes, int n_in,
                              void* d_out, int out_size, void* d_ws, size_t ws_size,
                              hipStream_t stream) {
  (void)in_sizes; (void)n_in; (void)out_size; (void)ws_size;
  const float* img  = (const float*)d_in[0];   // sample 0 only
  const float* cap  = (const float*)d_in[1];   // sample 0 only
  const float* c1w  = (const float*)d_in[2];
  const float* c1b  = (const float*)d_in[3];
  const float* c2w  = (const float*)d_in[4];
  const float* c2b  = (const float*)d_in[5];
  const float* cent = (const float*)d_in[6];
  const float* nvw  = (const float*)d_in[7];
  const float* nvb  = (const float*)d_in[8];
  const float* fcw  = (const float*)d_in[9];
  const float* fcb  = (const float*)d_in[10];
  const float* hidw = (const float*)d_in[11];
  const float* hidb = (const float*)d_in[12];
  const float* outw = (const float*)d_in[13];
  const float* outb = (const float*)d_in[14];

  float* ws   = (float*)d_ws;
  float* p1   = ws;               // 262144
  float* vacc = ws + 262144;      // 1024
  float* asum = ws + 263168;      // 64
  float* feat = ws + 263232;      // 512
  float* U    = ws + 263744;      // 63*512 = 32256
  float* H    = ws + 296000;      // 63*512 = 32256
  int*   done = (int*)(ws + 328256);

  k_front<<<1088, 256, 0, stream>>>(img, c1w, c1b, hidw, hidb, cap,
                                    p1, U, vacc, asum, H, done, (float*)d_out);
  k_mid<<<64, 256, 0, stream>>>(p1, c2w, c2b, nvw, nvb, cent, fcw, fcb,
                                vacc, asum, feat, done);
  k_back<<<67, 512, 0, stream>>>(hidw, U, feat, H, outw, outb, cap,
                                 (float*)d_out);
}